// Round 20
// baseline (452.141 us; speedup 1.0000x reference)
//
#include <hip/hip_runtime.h>
#include <hip/hip_bf16.h>
#include <hip/hip_fp16.h>
#include <math.h>

#define HDIM 128
#define INVD 16
#define DIN 272           // 2*H + INV
#define NKT 9             // K steps of 32 -> 288 (pad 272->288)
#define PACKSH (NKT * 8 * 64 * 8)   // 36864 shorts = 73728 B
#define WSTG 4608                   // shorts per wave stage: 8*1024B x + 1024B ea

#define TO_LDS(p) ((__attribute__((address_space(3))) void*)(p))
#define TO_GBL(p) ((const __attribute__((address_space(1))) void*)(p))

typedef __attribute__((ext_vector_type(4))) float f32x4;
typedef __attribute__((ext_vector_type(4))) unsigned u32x4;
typedef __attribute__((ext_vector_type(8))) short bf16x8;
typedef __attribute__((ext_vector_type(2))) __fp16 fp16x2;

__device__ inline short f2bf(float f) {
    union { float f; unsigned u; } v; v.f = f;
    unsigned r = v.u + 0x7FFFu + ((v.u >> 16) & 1u);   // RNE
    return (short)(r >> 16);
}

__device__ inline unsigned cvt_pk_bf16(float a, float b) {   // lo=a, hi=b, RNE
    unsigned r;
    asm("v_cvt_pk_bf16_f32 %0, %1, %2" : "=v"(r) : "v"(a), "v"(b));
    return r;
}

__device__ inline float fast_rcp(float x) {                  // v_rcp_f32, ~1ulp
    float r;
    asm("v_rcp_f32 %0, %1" : "=v"(r) : "v"(x));
    return r;
}

// ---- pre-pass: f32 -> bf16 (RNE), streaming ----
__global__ __launch_bounds__(256) void tobf16_kernel(const float* __restrict__ in,
                                                     unsigned short* __restrict__ o,
                                                     int n) {
    int i = (blockIdx.x * 256 + threadIdx.x) * 8;
    if (i < n) {
        f32x4 a = *(const f32x4*)(in + i);
        f32x4 b = *(const f32x4*)(in + i + 4);
        u32x4 r;
        r[0] = cvt_pk_bf16(a[0], a[1]);
        r[1] = cvt_pk_bf16(a[2], a[3]);
        r[2] = cvt_pk_bf16(b[0], b[1]);
        r[3] = cvt_pk_bf16(b[2], b[3]);
        *(u32x4*)(o + i) = r;
    }
}

// ---- prep: BN-fold W1 into bf16 MFMA fragment table (GLOBAL) + bias ----
__global__ __launch_bounds__(256) void prep_kernel(
    const float* __restrict__ bn_gamma, const float* __restrict__ bn_beta,
    const float* __restrict__ bn_mean,  const float* __restrict__ bn_var,
    const float* __restrict__ W1,       const float* __restrict__ b1,
    short* __restrict__ W1pack, float* __restrict__ biasTg)
{
    __shared__ float scl[DIN];
    __shared__ float shf[DIN];
    __shared__ float bias2[2][HDIM];
    const int tid = threadIdx.x;

    for (int c = tid; c < DIN; c += 256) {
        float sc = bn_gamma[c] * rsqrtf(bn_var[c] + 1e-5f);
        scl[c] = sc;
        shf[c] = bn_beta[c] - bn_mean[c] * sc;
    }
    __syncthreads();

    for (int f = tid; f < NKT * 8 * 64; f += 256) {
        const int kk  = f >> 9;
        const int cb  = (f >> 6) & 7;
        const int ln  = f & 63;
        const int k0  = kk * 32 + (ln >> 4) * 8;
        const int col = cb * 16 + (ln & 15);
        bf16x8 bv;
        #pragma unroll
        for (int j = 0; j < 8; ++j) {
            const int k = k0 + j;
            float v = (k < DIN) ? scl[k] * W1[k * HDIM + col] : 0.f;
            bv[j] = f2bf(v);
        }
        *(bf16x8*)&W1pack[f * 8] = bv;
    }
    {
        const int col  = tid & 127;
        const int half = tid >> 7;
        float s = 0.f;
        for (int k = half * 136; k < half * 136 + 136; ++k)
            s += shf[k] * W1[k * HDIM + col];
        bias2[half][col] = s;
    }
    __syncthreads();
    if (tid < HDIM) biasTg[tid] = b1[tid] + bias2[0][tid] + bias2[1][tid];
}

// ---- main: wave-private LDS staging via global_load_lds (0 dest VGPRs),
// btab from L2, counted vmcnt(16) so the stage wait never drains the 16
// atomics of the previous tile, 36.9KB LDS/block -> 4 blocks/CU (16 waves).
template<int MODE>   // 1 = staged + pk-f16 to ws, 0 = f32 atomics to out
__global__ __launch_bounds__(256, 4) void etnn_kernel(
    const float* __restrict__ x_send,
    const float* __restrict__ x_rec,
    const int*   __restrict__ index,     // [2][E] int32
    const float* __restrict__ edge_attr, // [E][16] f32
    const float* __restrict__ W2,
    const float* __restrict__ b2,
    const short* __restrict__ W1pack,    // [9][8][64][8] bf16, BN-folded
    const float* __restrict__ biasTg,    // [128]
    const unsigned short* __restrict__ xsb,  // [N][H] bf16 (MODE 1)
    const unsigned short* __restrict__ xrb,  // [N][H] bf16 (MODE 1)
    float* __restrict__ out,             // [N][H] (MODE 0)
    __half* __restrict__ ws,             // [N][H] f16 accumulator (MODE 1)
    int E, int nIter)
{
    __shared__ short stage[4 * WSTG];    // 36864 B: 4 waves x 9216 B

    const int tid = threadIdx.x;
    const int l  = tid & 63;
    const int lr = l & 15;     // edge slot within 16
    const int lg = l >> 4;     // k-group / row-group
    const int wid = tid >> 6;
    const int wsh = wid * WSTG;          // wave stage base (shorts)

    float biasv[8], w2v[8];
    #pragma unroll
    for (int cb = 0; cb < 8; ++cb) {
        biasv[cb] = biasTg[cb * 16 + lr];
        w2v[cb]   = W2[cb * 16 + lr];
    }
    const float b2v = b2[0];
    const bool evn = !(lr & 1);

    const int gw = blockIdx.x * 4 + wid;
    const int NW = gridDim.x * 4;

    if (gw >= nIter) return;

    if constexpr (MODE == 1) {
        // issue the 9 staging loads for one tile (per-lane global srcs,
        // wave-uniform LDS dest chunk; HW scatters lane i at dest+i*16)
        auto issueStage = [&](int isv, int irv, int pev) {
            #pragma unroll
            for (int kk = 0; kk < 4; ++kk)
                __builtin_amdgcn_global_load_lds(
                    TO_GBL(xsb + (size_t)isv * HDIM + kk * 32 + lg * 8),
                    TO_LDS(&stage[wsh + kk * 512]), 16, 0, 0);
            #pragma unroll
            for (int kk = 0; kk < 4; ++kk)
                __builtin_amdgcn_global_load_lds(
                    TO_GBL(xrb + (size_t)irv * HDIM + kk * 32 + lg * 8),
                    TO_LDS(&stage[wsh + (kk + 4) * 512]), 16, 0, 0);
            __builtin_amdgcn_global_load_lds(
                TO_GBL(edge_attr + (size_t)pev * INVD + (l & 3) * 4),
                TO_LDS(&stage[wsh + 8 * 512]), 16, 0, 0);
        };

        auto ldIdx = [&](int itx, int& pcv, int& isv, int& irv, int& pev) {
            int pos = itx * 16 + lr;
            pcv = (pos < E && pos >= 0) ? pos : E - 1;
            isv = index[pcv];
            irv = index[E + pcv];
            int pe = itx * 16 + (l >> 2);
            pev = (pe < E && pe >= 0) ? pe : E - 1;
        };

        // ---- prologue: stage tile gw, full drain once; prefetch next idx ----
        int pc0, is0, ir0, pe0;
        ldIdx(gw, pc0, is0, ir0, pe0);
        issueStage(is0, ir0, pe0);
        int pc1, is1, ir1, pe1;
        ldIdx(gw + NW, pc1, is1, ir1, pe1);
        asm volatile("s_waitcnt vmcnt(0)" ::: "memory");

        for (int it = gw; it < nIter; it += NW) {
            const int e0 = it * 16;
            // stage(t) complete: it is older than the newest 16 vmem ops
            // (prev tile's atomics); vmcnt retires in order.
            asm volatile("s_waitcnt vmcnt(16)" ::: "memory");

            const int irc = ir0;

            // -------- MFMA: A from LDS stage, B from L2 --------
            f32x4 acc[8];
            #pragma unroll
            for (int cb = 0; cb < 8; ++cb) acc[cb] = (f32x4){0.f, 0.f, 0.f, 0.f};

            #pragma unroll
            for (int kk = 0; kk < NKT; ++kk) {
                union { bf16x8 v; unsigned u[4]; } a;
                if (kk < 8) {
                    a.v = *(const bf16x8*)&stage[wsh + kk * 512 + l * 8];
                } else {
                    if (lg < 2) {
                        const float* ef = (const float*)((const char*)stage +
                                          wsh * 2 + 8192 + lr * 64 + lg * 32);
                        f32x4 ea = *(const f32x4*)ef;
                        f32x4 eb = *(const f32x4*)(ef + 4);
                        a.u[0] = cvt_pk_bf16(ea[0], ea[1]);
                        a.u[1] = cvt_pk_bf16(ea[2], ea[3]);
                        a.u[2] = cvt_pk_bf16(eb[0], eb[1]);
                        a.u[3] = cvt_pk_bf16(eb[2], eb[3]);
                    } else {
                        a.u[0] = 0; a.u[1] = 0; a.u[2] = 0; a.u[3] = 0;
                    }
                }
                #pragma unroll
                for (int cb = 0; cb < 8; ++cb) {
                    bf16x8 b = *(const bf16x8*)&W1pack[((kk * 8 + cb) * 64 + l) * 8];
                    acc[cb] = __builtin_amdgcn_mfma_f32_16x16x32_bf16(a.v, b, acc[cb], 0, 0, 0);
                }
            }

            // -------- SiLU + gate dot (16-lane reduce) --------
            float p[4] = {0.f, 0.f, 0.f, 0.f};
            #pragma unroll
            for (int cb = 0; cb < 8; ++cb) {
                #pragma unroll
                for (int q = 0; q < 4; ++q) {
                    float z = acc[cb][q] + biasv[cb];
                    float m = z * fast_rcp(1.f + __expf(-z));   // SiLU
                    acc[cb][q] = m;
                    p[q] += m * w2v[cb];
                }
            }
            #pragma unroll
            for (int q = 0; q < 4; ++q) {
                p[q] += __shfl_xor(p[q], 1, 64);
                p[q] += __shfl_xor(p[q], 2, 64);
                p[q] += __shfl_xor(p[q], 4, 64);
                p[q] += __shfl_xor(p[q], 8, 64);
            }

            // -------- prefetch idx(t+2NW), stage(t+NW), THEN atomics(t) ----
            const bool more = (it + NW) < nIter;     // wave-uniform
            int pc2 = pc1, is2 = is1, ir2 = ir1, pe2 = pe1;
            if (more) {
                issueStage(is1, ir1, pe1);
                ldIdx(it + 2 * NW, pc2, is2, ir2, pe2);
            }

            #pragma unroll
            for (int q = 0; q < 4; ++q) {
                const int row = lg * 4 + q;
                if (e0 + row < E) {
                    const int irq = __shfl(irc, row, 64);
                    const float g = fast_rcp(1.f + __expf(-(p[q] + b2v)));
                    float m[8];
                    #pragma unroll
                    for (int cb = 0; cb < 8; ++cb) m[cb] = acc[cb][q] * g;
                    #pragma unroll
                    for (int c = 0; c < 4; ++c) {
                        float x0 = __shfl_xor(m[2 * c],     1, 64);
                        float x1 = __shfl_xor(m[2 * c + 1], 1, 64);
                        float va = evn ? m[2 * c] : x1;
                        float vb = evn ? x0       : m[2 * c + 1];
                        union { fp16x2 h; unsigned u; } pk;
                        pk.h = __builtin_amdgcn_cvt_pkrtz(va, vb);
                        const int col0 = evn ? (32 * c + lr) : (32 * c + 15 + lr);
                        unsigned long long a =
                            (unsigned long long)(ws + (size_t)irq * HDIM + col0);
                        asm volatile("global_atomic_pk_add_f16 %0, %1, off"
                                     :: "v"(a), "v"(pk.u) : "memory");
                    }
                }
            }

            pc0 = pc1; is0 = is1; ir0 = ir1; pe0 = pe1;
            pc1 = pc2; is1 = is2; ir1 = ir2; pe1 = pe2;
        }
    } else {
        // ---------- MODE 0 fallback: f32 gather, f32 atomics to out ----------
        for (int it = gw; it < nIter; it += NW) {
            const int e0 = it * 16;
            int pos = e0 + lr;
            int pc = (pos < E) ? pos : E - 1;
            int is = index[pc];
            int ir = index[E + pc];
            const f32x4* ps = (const f32x4*)(x_send + (size_t)is * HDIM);
            const f32x4* pr = (const f32x4*)(x_rec  + (size_t)ir * HDIM);
            f32x4 LsF[8], LrF[8], La[2];
            #pragma unroll
            for (int kk = 0; kk < 4; ++kk) {
                LsF[kk * 2]     = ps[kk * 8 + lg * 2];
                LsF[kk * 2 + 1] = ps[kk * 8 + lg * 2 + 1];
                LrF[kk * 2]     = pr[kk * 8 + lg * 2];
                LrF[kk * 2 + 1] = pr[kk * 8 + lg * 2 + 1];
            }
            if (lg < 2) {
                const f32x4* pa = (const f32x4*)(edge_attr + (size_t)pc * INVD + lg * 8);
                La[0] = pa[0]; La[1] = pa[1];
            } else {
                La[0] = (f32x4){0.f, 0.f, 0.f, 0.f};
                La[1] = (f32x4){0.f, 0.f, 0.f, 0.f};
            }

            f32x4 acc[8];
            #pragma unroll
            for (int cb = 0; cb < 8; ++cb) acc[cb] = (f32x4){0.f, 0.f, 0.f, 0.f};
            #pragma unroll
            for (int kk = 0; kk < NKT; ++kk) {
                f32x4 lo = (kk < 4) ? LsF[kk * 2]     : (kk < 8) ? LrF[(kk - 4) * 2]     : La[0];
                f32x4 hi = (kk < 4) ? LsF[kk * 2 + 1] : (kk < 8) ? LrF[(kk - 4) * 2 + 1] : La[1];
                union { bf16x8 v; unsigned u[4]; } a;
                a.u[0] = cvt_pk_bf16(lo[0], lo[1]);
                a.u[1] = cvt_pk_bf16(lo[2], lo[3]);
                a.u[2] = cvt_pk_bf16(hi[0], hi[1]);
                a.u[3] = cvt_pk_bf16(hi[2], hi[3]);
                #pragma unroll
                for (int cb = 0; cb < 8; ++cb) {
                    bf16x8 b = *(const bf16x8*)&W1pack[((kk * 8 + cb) * 64 + l) * 8];
                    acc[cb] = __builtin_amdgcn_mfma_f32_16x16x32_bf16(a.v, b, acc[cb], 0, 0, 0);
                }
            }
            float p[4] = {0.f, 0.f, 0.f, 0.f};
            #pragma unroll
            for (int cb = 0; cb < 8; ++cb) {
                #pragma unroll
                for (int q = 0; q < 4; ++q) {
                    float z = acc[cb][q] + biasv[cb];
                    float m = z * fast_rcp(1.f + __expf(-z));
                    acc[cb][q] = m;
                    p[q] += m * w2v[cb];
                }
            }
            #pragma unroll
            for (int q = 0; q < 4; ++q) {
                p[q] += __shfl_xor(p[q], 1, 64);
                p[q] += __shfl_xor(p[q], 2, 64);
                p[q] += __shfl_xor(p[q], 4, 64);
                p[q] += __shfl_xor(p[q], 8, 64);
            }
            #pragma unroll
            for (int q = 0; q < 4; ++q) {
                const int row = lg * 4 + q;
                if (e0 + row < E) {
                    const int irq = __shfl(ir, row, 64);
                    const float g = fast_rcp(1.f + __expf(-(p[q] + b2v)));
                    float* orow = out + (size_t)irq * HDIM + lr;
                    #pragma unroll
                    for (int cb = 0; cb < 8; ++cb)
                        atomicAdd(orow + cb * 16, acc[cb][q] * g);
                }
            }
        }
    }
}

__global__ __launch_bounds__(256) void cvt_kernel(const __half* __restrict__ ws,
                                                  float* __restrict__ out, int n) {
    int i = (blockIdx.x * 256 + threadIdx.x) * 4;
    if (i < n) {
        const __half2* p = (const __half2*)(ws + i);
        float2 a = __half22float2(p[0]);
        float2 b = __half22float2(p[1]);
        f32x4 v = {a.x, a.y, b.x, b.y};
        *(f32x4*)(out + i) = v;
    }
}

extern "C" void kernel_launch(void* const* d_in, const int* in_sizes, int n_in,
                              void* d_out, int out_size, void* d_ws, size_t ws_size,
                              hipStream_t stream) {
    const float* x_send    = (const float*)d_in[0];
    const float* x_rec     = (const float*)d_in[1];
    const int*   index     = (const int*)d_in[2];
    const float* edge_attr = (const float*)d_in[3];
    const float* bn_gamma  = (const float*)d_in[4];
    const float* bn_beta   = (const float*)d_in[5];
    const float* bn_mean   = (const float*)d_in[6];
    const float* bn_var    = (const float*)d_in[7];
    const float* W1        = (const float*)d_in[8];
    const float* b1        = (const float*)d_in[9];
    const float* W2        = (const float*)d_in[10];
    const float* b2        = (const float*)d_in[11];
    float* out = (float*)d_out;

    const int E = in_sizes[3] / INVD;
    const int N = in_sizes[0] / HDIM;
    const int nIter = (E + 15) / 16;
    const int nElem = N * HDIM;

    const size_t accBytes  = (size_t)nElem * sizeof(__half);
    const size_t accAl     = (accBytes + 255) & ~(size_t)255;
    const size_t bfBytes   = (size_t)nElem * sizeof(unsigned short);
    const size_t bfAl      = (bfBytes + 255) & ~(size_t)255;
    const size_t packBytes = (size_t)PACKSH * sizeof(short) + HDIM * sizeof(float);
    const size_t packAl    = (packBytes + 255) & ~(size_t)255;

    if (ws_size >= accAl + 2 * bfAl + packAl) {
        __half* ws = (__half*)d_ws;
        unsigned short* xsb = (unsigned short*)((char*)d_ws + accAl);
        unsigned short* xrb = (unsigned short*)((char*)d_ws + accAl + bfAl);
        short* pack  = (short*)((char*)d_ws + accAl + 2 * bfAl);
        float* biasg = (float*)(pack + PACKSH);
        hipMemsetAsync(ws, 0, accBytes, stream);
        const int cb = (nElem / 8 + 255) / 256;
        tobf16_kernel<<<cb, 256, 0, stream>>>(x_send, xsb, nElem);
        tobf16_kernel<<<cb, 256, 0, stream>>>(x_rec,  xrb, nElem);
        prep_kernel<<<1, 256, 0, stream>>>(bn_gamma, bn_beta, bn_mean, bn_var,
                                           W1, b1, pack, biasg);
        etnn_kernel<1><<<1024, 256, 0, stream>>>(x_send, x_rec, index, edge_attr,
                                                 W2, b2, pack, biasg, xsb, xrb,
                                                 out, ws, E, nIter);
        cvt_kernel<<<(nElem / 4 + 255) / 256, 256, 0, stream>>>(ws, out, nElem);
    } else {
        short* pack  = (short*)d_ws;
        float* biasg = (float*)(pack + PACKSH);
        hipMemsetAsync(d_out, 0, (size_t)out_size * sizeof(float), stream);
        prep_kernel<<<1, 256, 0, stream>>>(bn_gamma, bn_beta, bn_mean, bn_var,
                                           W1, b1, pack, biasg);
        etnn_kernel<0><<<1024, 256, 0, stream>>>(x_send, x_rec, index, edge_attr,
                                                 W2, b2, pack, biasg, nullptr, nullptr,
                                                 out, nullptr, E, nIter);
    }
}

// Round 21
// 274.484 us; speedup vs baseline: 1.6472x; 1.6472x over previous
//
#include <hip/hip_runtime.h>
#include <hip/hip_bf16.h>
#include <hip/hip_fp16.h>
#include <math.h>

#define HDIM 128
#define INVD 16
#define DIN 272           // 2*H + INV
#define NKT 9             // K steps of 32 -> 288 (pad 272->288)
#define PACKSH (NKT * 8 * 64 * 8)   // 36864 shorts = 73728 B
#define WSTG 4608                   // shorts per wave stage: 8*1024B x + 1024B ea

#define TO_LDS(p) ((__attribute__((address_space(3))) void*)(p))
#define TO_GBL(p) ((const __attribute__((address_space(1))) void*)(p))

typedef __attribute__((ext_vector_type(4))) float f32x4;
typedef __attribute__((ext_vector_type(4))) unsigned u32x4;
typedef __attribute__((ext_vector_type(8))) short bf16x8;
typedef __attribute__((ext_vector_type(2))) __fp16 fp16x2;

__device__ inline short f2bf(float f) {
    union { float f; unsigned u; } v; v.f = f;
    unsigned r = v.u + 0x7FFFu + ((v.u >> 16) & 1u);   // RNE
    return (short)(r >> 16);
}

__device__ inline unsigned cvt_pk_bf16(float a, float b) {   // lo=a, hi=b, RNE
    unsigned r;
    asm("v_cvt_pk_bf16_f32 %0, %1, %2" : "=v"(r) : "v"(a), "v"(b));
    return r;
}

__device__ inline float fast_rcp(float x) {                  // v_rcp_f32, ~1ulp
    float r;
    asm("v_rcp_f32 %0, %1" : "=v"(r) : "v"(x));
    return r;
}

// ---- pre-pass: f32 -> bf16 (RNE), streaming ----
__global__ __launch_bounds__(256) void tobf16_kernel(const float* __restrict__ in,
                                                     unsigned short* __restrict__ o,
                                                     int n) {
    int i = (blockIdx.x * 256 + threadIdx.x) * 8;
    if (i < n) {
        f32x4 a = *(const f32x4*)(in + i);
        f32x4 b = *(const f32x4*)(in + i + 4);
        u32x4 r;
        r[0] = cvt_pk_bf16(a[0], a[1]);
        r[1] = cvt_pk_bf16(a[2], a[3]);
        r[2] = cvt_pk_bf16(b[0], b[1]);
        r[3] = cvt_pk_bf16(b[2], b[3]);
        *(u32x4*)(o + i) = r;
    }
}

// ---- prep: BN-fold W1 into bf16 MFMA fragment table (GLOBAL) + bias ----
__global__ __launch_bounds__(256) void prep_kernel(
    const float* __restrict__ bn_gamma, const float* __restrict__ bn_beta,
    const float* __restrict__ bn_mean,  const float* __restrict__ bn_var,
    const float* __restrict__ W1,       const float* __restrict__ b1,
    short* __restrict__ W1pack, float* __restrict__ biasTg)
{
    __shared__ float scl[DIN];
    __shared__ float shf[DIN];
    __shared__ float bias2[2][HDIM];
    const int tid = threadIdx.x;

    for (int c = tid; c < DIN; c += 256) {
        float sc = bn_gamma[c] * rsqrtf(bn_var[c] + 1e-5f);
        scl[c] = sc;
        shf[c] = bn_beta[c] - bn_mean[c] * sc;
    }
    __syncthreads();

    for (int f = tid; f < NKT * 8 * 64; f += 256) {
        const int kk  = f >> 9;
        const int cb  = (f >> 6) & 7;
        const int ln  = f & 63;
        const int k0  = kk * 32 + (ln >> 4) * 8;
        const int col = cb * 16 + (ln & 15);
        bf16x8 bv;
        #pragma unroll
        for (int j = 0; j < 8; ++j) {
            const int k = k0 + j;
            float v = (k < DIN) ? scl[k] * W1[k * HDIM + col] : 0.f;
            bv[j] = f2bf(v);
        }
        *(bf16x8*)&W1pack[f * 8] = bv;
    }
    {
        const int col  = tid & 127;
        const int half = tid >> 7;
        float s = 0.f;
        for (int k = half * 136; k < half * 136 + 136; ++k)
            s += shf[k] * W1[k * HDIM + col];
        bias2[half][col] = s;
    }
    __syncthreads();
    if (tid < HDIM) biasTg[tid] = b1[tid] + bias2[0][tid] + bias2[1][tid];
}

// ---- main: wave-private LDS staging via global_load_lds (0 dest VGPRs),
// btab from L2, counted vmcnt(16) so the stage wait never drains the 16
// atomics of the previous tile. launch_bounds(256,2): the only bound that
// never spilled; staging removes the gather buffer so real need ~100 VGPR,
// letting HW reach 4 waves/SIMD on its own (LDS 36.9KB allows 4 blocks/CU).
template<int MODE>   // 1 = staged + pk-f16 to ws, 0 = f32 atomics to out
__global__ __launch_bounds__(256, 2) void etnn_kernel(
    const float* __restrict__ x_send,
    const float* __restrict__ x_rec,
    const int*   __restrict__ index,     // [2][E] int32
    const float* __restrict__ edge_attr, // [E][16] f32
    const float* __restrict__ W2,
    const float* __restrict__ b2,
    const short* __restrict__ W1pack,    // [9][8][64][8] bf16, BN-folded
    const float* __restrict__ biasTg,    // [128]
    const unsigned short* __restrict__ xsb,  // [N][H] bf16 (MODE 1)
    const unsigned short* __restrict__ xrb,  // [N][H] bf16 (MODE 1)
    float* __restrict__ out,             // [N][H] (MODE 0)
    __half* __restrict__ ws,             // [N][H] f16 accumulator (MODE 1)
    int E, int nIter)
{
    __shared__ short stage[4 * WSTG];    // 36864 B: 4 waves x 9216 B

    const int tid = threadIdx.x;
    const int l  = tid & 63;
    const int lr = l & 15;     // edge slot within 16
    const int lg = l >> 4;     // k-group / row-group
    const int wid = tid >> 6;
    const int wsh = wid * WSTG;          // wave stage base (shorts)

    float biasv[8], w2v[8];
    #pragma unroll
    for (int cb = 0; cb < 8; ++cb) {
        biasv[cb] = biasTg[cb * 16 + lr];
        w2v[cb]   = W2[cb * 16 + lr];
    }
    const float b2v = b2[0];
    const bool evn = !(lr & 1);

    const int gw = blockIdx.x * 4 + wid;
    const int NW = gridDim.x * 4;

    if (gw >= nIter) return;

    if constexpr (MODE == 1) {
        // issue the 9 staging loads for one tile (per-lane global srcs,
        // wave-uniform LDS dest chunk; HW scatters lane i at dest+i*16)
        auto issueStage = [&](int isv, int irv, int pev) {
            #pragma unroll
            for (int kk = 0; kk < 4; ++kk)
                __builtin_amdgcn_global_load_lds(
                    TO_GBL(xsb + (size_t)isv * HDIM + kk * 32 + lg * 8),
                    TO_LDS(&stage[wsh + kk * 512]), 16, 0, 0);
            #pragma unroll
            for (int kk = 0; kk < 4; ++kk)
                __builtin_amdgcn_global_load_lds(
                    TO_GBL(xrb + (size_t)irv * HDIM + kk * 32 + lg * 8),
                    TO_LDS(&stage[wsh + (kk + 4) * 512]), 16, 0, 0);
            __builtin_amdgcn_global_load_lds(
                TO_GBL(edge_attr + (size_t)pev * INVD + (l & 3) * 4),
                TO_LDS(&stage[wsh + 8 * 512]), 16, 0, 0);
        };

        auto ldIdx = [&](int itx, int& pcv, int& isv, int& irv, int& pev) {
            int pos = itx * 16 + lr;
            pcv = (pos < E && pos >= 0) ? pos : E - 1;
            isv = index[pcv];
            irv = index[E + pcv];
            int pe = itx * 16 + (l >> 2);
            pev = (pe < E && pe >= 0) ? pe : E - 1;
        };

        // ---- prologue: stage tile gw, full drain once; prefetch next idx ----
        int pc0, is0, ir0, pe0;
        ldIdx(gw, pc0, is0, ir0, pe0);
        issueStage(is0, ir0, pe0);
        int pc1, is1, ir1, pe1;
        ldIdx(gw + NW, pc1, is1, ir1, pe1);
        asm volatile("s_waitcnt vmcnt(0)" ::: "memory");

        for (int it = gw; it < nIter; it += NW) {
            const int e0 = it * 16;
            // stage(t) complete: it is older than the newest 16 vmem ops
            // (prev tile's atomics); vmcnt retires in order.
            asm volatile("s_waitcnt vmcnt(16)" ::: "memory");

            const int irc = ir0;

            // -------- MFMA: A from LDS stage, B from L2 --------
            f32x4 acc[8];
            #pragma unroll
            for (int cb = 0; cb < 8; ++cb) acc[cb] = (f32x4){0.f, 0.f, 0.f, 0.f};

            #pragma unroll
            for (int kk = 0; kk < NKT; ++kk) {
                union { bf16x8 v; unsigned u[4]; } a;
                if (kk < 8) {
                    a.v = *(const bf16x8*)&stage[wsh + kk * 512 + l * 8];
                } else {
                    if (lg < 2) {
                        const float* ef = (const float*)((const char*)stage +
                                          wsh * 2 + 8192 + lr * 64 + lg * 32);
                        f32x4 ea = *(const f32x4*)ef;
                        f32x4 eb = *(const f32x4*)(ef + 4);
                        a.u[0] = cvt_pk_bf16(ea[0], ea[1]);
                        a.u[1] = cvt_pk_bf16(ea[2], ea[3]);
                        a.u[2] = cvt_pk_bf16(eb[0], eb[1]);
                        a.u[3] = cvt_pk_bf16(eb[2], eb[3]);
                    } else {
                        a.u[0] = 0; a.u[1] = 0; a.u[2] = 0; a.u[3] = 0;
                    }
                }
                #pragma unroll
                for (int cb = 0; cb < 8; ++cb) {
                    bf16x8 b = *(const bf16x8*)&W1pack[((kk * 8 + cb) * 64 + l) * 8];
                    acc[cb] = __builtin_amdgcn_mfma_f32_16x16x32_bf16(a.v, b, acc[cb], 0, 0, 0);
                }
            }

            // -------- SiLU + gate dot (16-lane reduce) --------
            float p[4] = {0.f, 0.f, 0.f, 0.f};
            #pragma unroll
            for (int cb = 0; cb < 8; ++cb) {
                #pragma unroll
                for (int q = 0; q < 4; ++q) {
                    float z = acc[cb][q] + biasv[cb];
                    float m = z * fast_rcp(1.f + __expf(-z));   // SiLU
                    acc[cb][q] = m;
                    p[q] += m * w2v[cb];
                }
            }
            #pragma unroll
            for (int q = 0; q < 4; ++q) {
                p[q] += __shfl_xor(p[q], 1, 64);
                p[q] += __shfl_xor(p[q], 2, 64);
                p[q] += __shfl_xor(p[q], 4, 64);
                p[q] += __shfl_xor(p[q], 8, 64);
            }

            // -------- prefetch idx(t+2NW), stage(t+NW), THEN atomics(t) ----
            const bool more = (it + NW) < nIter;     // wave-uniform
            int pc2 = pc1, is2 = is1, ir2 = ir1, pe2 = pe1;
            if (more) {
                issueStage(is1, ir1, pe1);
                ldIdx(it + 2 * NW, pc2, is2, ir2, pe2);
            }

            #pragma unroll
            for (int q = 0; q < 4; ++q) {
                const int row = lg * 4 + q;
                if (e0 + row < E) {
                    const int irq = __shfl(irc, row, 64);
                    const float g = fast_rcp(1.f + __expf(-(p[q] + b2v)));
                    float m[8];
                    #pragma unroll
                    for (int cb = 0; cb < 8; ++cb) m[cb] = acc[cb][q] * g;
                    #pragma unroll
                    for (int c = 0; c < 4; ++c) {
                        float x0 = __shfl_xor(m[2 * c],     1, 64);
                        float x1 = __shfl_xor(m[2 * c + 1], 1, 64);
                        float va = evn ? m[2 * c] : x1;
                        float vb = evn ? x0       : m[2 * c + 1];
                        union { fp16x2 h; unsigned u; } pk;
                        pk.h = __builtin_amdgcn_cvt_pkrtz(va, vb);
                        const int col0 = evn ? (32 * c + lr) : (32 * c + 15 + lr);
                        unsigned long long a =
                            (unsigned long long)(ws + (size_t)irq * HDIM + col0);
                        asm volatile("global_atomic_pk_add_f16 %0, %1, off"
                                     :: "v"(a), "v"(pk.u) : "memory");
                    }
                }
            }

            pc0 = pc1; is0 = is1; ir0 = ir1; pe0 = pe1;
            pc1 = pc2; is1 = is2; ir1 = ir2; pe1 = pe2;
        }
    } else {
        // ---------- MODE 0 fallback: f32 gather, f32 atomics to out ----------
        for (int it = gw; it < nIter; it += NW) {
            const int e0 = it * 16;
            int pos = e0 + lr;
            int pc = (pos < E) ? pos : E - 1;
            int is = index[pc];
            int ir = index[E + pc];
            const f32x4* ps = (const f32x4*)(x_send + (size_t)is * HDIM);
            const f32x4* pr = (const f32x4*)(x_rec  + (size_t)ir * HDIM);
            f32x4 LsF[8], LrF[8], La[2];
            #pragma unroll
            for (int kk = 0; kk < 4; ++kk) {
                LsF[kk * 2]     = ps[kk * 8 + lg * 2];
                LsF[kk * 2 + 1] = ps[kk * 8 + lg * 2 + 1];
                LrF[kk * 2]     = pr[kk * 8 + lg * 2];
                LrF[kk * 2 + 1] = pr[kk * 8 + lg * 2 + 1];
            }
            if (lg < 2) {
                const f32x4* pa = (const f32x4*)(edge_attr + (size_t)pc * INVD + lg * 8);
                La[0] = pa[0]; La[1] = pa[1];
            } else {
                La[0] = (f32x4){0.f, 0.f, 0.f, 0.f};
                La[1] = (f32x4){0.f, 0.f, 0.f, 0.f};
            }

            f32x4 acc[8];
            #pragma unroll
            for (int cb = 0; cb < 8; ++cb) acc[cb] = (f32x4){0.f, 0.f, 0.f, 0.f};
            #pragma unroll
            for (int kk = 0; kk < NKT; ++kk) {
                f32x4 lo = (kk < 4) ? LsF[kk * 2]     : (kk < 8) ? LrF[(kk - 4) * 2]     : La[0];
                f32x4 hi = (kk < 4) ? LsF[kk * 2 + 1] : (kk < 8) ? LrF[(kk - 4) * 2 + 1] : La[1];
                union { bf16x8 v; unsigned u[4]; } a;
                a.u[0] = cvt_pk_bf16(lo[0], lo[1]);
                a.u[1] = cvt_pk_bf16(lo[2], lo[3]);
                a.u[2] = cvt_pk_bf16(hi[0], hi[1]);
                a.u[3] = cvt_pk_bf16(hi[2], hi[3]);
                #pragma unroll
                for (int cb = 0; cb < 8; ++cb) {
                    bf16x8 b = *(const bf16x8*)&W1pack[((kk * 8 + cb) * 64 + l) * 8];
                    acc[cb] = __builtin_amdgcn_mfma_f32_16x16x32_bf16(a.v, b, acc[cb], 0, 0, 0);
                }
            }
            float p[4] = {0.f, 0.f, 0.f, 0.f};
            #pragma unroll
            for (int cb = 0; cb < 8; ++cb) {
                #pragma unroll
                for (int q = 0; q < 4; ++q) {
                    float z = acc[cb][q] + biasv[cb];
                    float m = z * fast_rcp(1.f + __expf(-z));
                    acc[cb][q] = m;
                    p[q] += m * w2v[cb];
                }
            }
            #pragma unroll
            for (int q = 0; q < 4; ++q) {
                p[q] += __shfl_xor(p[q], 1, 64);
                p[q] += __shfl_xor(p[q], 2, 64);
                p[q] += __shfl_xor(p[q], 4, 64);
                p[q] += __shfl_xor(p[q], 8, 64);
            }
            #pragma unroll
            for (int q = 0; q < 4; ++q) {
                const int row = lg * 4 + q;
                if (e0 + row < E) {
                    const int irq = __shfl(ir, row, 64);
                    const float g = fast_rcp(1.f + __expf(-(p[q] + b2v)));
                    float* orow = out + (size_t)irq * HDIM + lr;
                    #pragma unroll
                    for (int cb = 0; cb < 8; ++cb)
                        atomicAdd(orow + cb * 16, acc[cb][q] * g);
                }
            }
        }
    }
}

__global__ __launch_bounds__(256) void cvt_kernel(const __half* __restrict__ ws,
                                                  float* __restrict__ out, int n) {
    int i = (blockIdx.x * 256 + threadIdx.x) * 4;
    if (i < n) {
        const __half2* p = (const __half2*)(ws + i);
        float2 a = __half22float2(p[0]);
        float2 b = __half22float2(p[1]);
        f32x4 v = {a.x, a.y, b.x, b.y};
        *(f32x4*)(out + i) = v;
    }
}

extern "C" void kernel_launch(void* const* d_in, const int* in_sizes, int n_in,
                              void* d_out, int out_size, void* d_ws, size_t ws_size,
                              hipStream_t stream) {
    const float* x_send    = (const float*)d_in[0];
    const float* x_rec     = (const float*)d_in[1];
    const int*   index     = (const int*)d_in[2];
    const float* edge_attr = (const float*)d_in[3];
    const float* bn_gamma  = (const float*)d_in[4];
    const float* bn_beta   = (const float*)d_in[5];
    const float* bn_mean   = (const float*)d_in[6];
    const float* bn_var    = (const float*)d_in[7];
    const float* W1        = (const float*)d_in[8];
    const float* b1        = (const float*)d_in[9];
    const float* W2        = (const float*)d_in[10];
    const float* b2        = (const float*)d_in[11];
    float* out = (float*)d_out;

    const int E = in_sizes[3] / INVD;
    const int N = in_sizes[0] / HDIM;
    const int nIter = (E + 15) / 16;
    const int nElem = N * HDIM;

    const size_t accBytes  = (size_t)nElem * sizeof(__half);
    const size_t accAl     = (accBytes + 255) & ~(size_t)255;
    const size_t bfBytes   = (size_t)nElem * sizeof(unsigned short);
    const size_t bfAl      = (bfBytes + 255) & ~(size_t)255;
    const size_t packBytes = (size_t)PACKSH * sizeof(short) + HDIM * sizeof(float);
    const size_t packAl    = (packBytes + 255) & ~(size_t)255;

    if (ws_size >= accAl + 2 * bfAl + packAl) {
        __half* ws = (__half*)d_ws;
        unsigned short* xsb = (unsigned short*)((char*)d_ws + accAl);
        unsigned short* xrb = (unsigned short*)((char*)d_ws + accAl + bfAl);
        short* pack  = (short*)((char*)d_ws + accAl + 2 * bfAl);
        float* biasg = (float*)(pack + PACKSH);
        hipMemsetAsync(ws, 0, accBytes, stream);
        const int cb = (nElem / 8 + 255) / 256;
        tobf16_kernel<<<cb, 256, 0, stream>>>(x_send, xsb, nElem);
        tobf16_kernel<<<cb, 256, 0, stream>>>(x_rec,  xrb, nElem);
        prep_kernel<<<1, 256, 0, stream>>>(bn_gamma, bn_beta, bn_mean, bn_var,
                                           W1, b1, pack, biasg);
        etnn_kernel<1><<<1024, 256, 0, stream>>>(x_send, x_rec, index, edge_attr,
                                                 W2, b2, pack, biasg, xsb, xrb,
                                                 out, ws, E, nIter);
        cvt_kernel<<<(nElem / 4 + 255) / 256, 256, 0, stream>>>(ws, out, nElem);
    } else {
        short* pack  = (short*)d_ws;
        float* biasg = (float*)(pack + PACKSH);
        hipMemsetAsync(d_out, 0, (size_t)out_size * sizeof(float), stream);
        prep_kernel<<<1, 256, 0, stream>>>(bn_gamma, bn_beta, bn_mean, bn_var,
                                           W1, b1, pack, biasg);
        etnn_kernel<0><<<1024, 256, 0, stream>>>(x_send, x_rec, index, edge_attr,
                                                 W2, b2, pack, biasg, nullptr, nullptr,
                                                 out, nullptr, E, nIter);
    }
}

// Round 22
// 193.127 us; speedup vs baseline: 2.3412x; 1.4213x over previous
//
#include <hip/hip_runtime.h>
#include <hip/hip_bf16.h>
#include <hip/hip_fp16.h>
#include <math.h>

#define HDIM 128
#define INVD 16
#define DIN 272           // 2*H + INV
#define NKT 9             // K steps of 32 -> 288 (pad 272->288)

typedef __attribute__((ext_vector_type(4))) float f32x4;
typedef __attribute__((ext_vector_type(8))) short bf16x8;
typedef __attribute__((ext_vector_type(2))) __fp16 fp16x2;

__device__ inline short f2bf(float f) {
    union { float f; unsigned u; } v; v.f = f;
    unsigned r = v.u + 0x7FFFu + ((v.u >> 16) & 1u);   // RNE
    return (short)(r >> 16);
}

// Barrier-free main loop: each wave owns 16 edges x 128 cols.
// W1 (BN-scale folded, bf16) pre-packed in LDS as MFMA B-fragments, read-only.
// Scatter: in-register f16 pair packing -> global_atomic_pk_add_f16, each
// wave-instruction covers 4 node rows x 64 contiguous bytes (4 full lines).
// This structure sits at the measured memory-side atomic wall (~186 G ops/s):
// 32M pk-atomics ~= 172us main + ~21us streaming aux = ~194us total floor.
template<bool WS>
__global__ __launch_bounds__(256, 2) void etnn_kernel(
    const float* __restrict__ x_send,
    const float* __restrict__ x_rec,
    const int*   __restrict__ index,     // [2][E] int32
    const float* __restrict__ edge_attr, // [E][16]
    const float* __restrict__ bn_gamma,
    const float* __restrict__ bn_beta,
    const float* __restrict__ bn_mean,
    const float* __restrict__ bn_var,
    const float* __restrict__ W1,        // [DIN][H]
    const float* __restrict__ b1,
    const float* __restrict__ W2,
    const float* __restrict__ b2,
    float* __restrict__ out,             // [N][H] (fallback path)
    __half* __restrict__ ws,             // [N][H] f16 accumulator (WS path)
    int E, int nIter)
{
    // [kk][cb][lane][8 bf16] : 9*8*64*8 shorts = 73728 B
    __shared__ short btab[NKT * 8 * 64 * 8];
    __shared__ float scl[DIN];
    __shared__ float shf[DIN];
    __shared__ float bias2[2][HDIM];
    __shared__ float biasT[HDIM];

    const int tid = threadIdx.x;
    const int l  = tid & 63;
    const int lr = l & 15;     // edge slot within 16 (A rows / C cols)
    const int lg = l >> 4;     // k-group (A) / row-group (C)

    // ---- BN constants ----
    for (int c = tid; c < DIN; c += 256) {
        float sc = bn_gamma[c] * rsqrtf(bn_var[c] + 1e-5f);
        scl[c] = sc;
        shf[c] = bn_beta[c] - bn_mean[c] * sc;
    }
    __syncthreads();

    // ---- build B-fragment table (BN scale folded into W) ----
    for (int f = tid; f < NKT * 8 * 64; f += 256) {
        const int kk  = f >> 9;          // /(8*64)
        const int cb  = (f >> 6) & 7;
        const int ln  = f & 63;
        const int k0  = kk * 32 + (ln >> 4) * 8;
        const int col = cb * 16 + (ln & 15);
        bf16x8 bv;
        #pragma unroll
        for (int j = 0; j < 8; ++j) {
            const int k = k0 + j;
            float v = (k < DIN) ? scl[k] * W1[k * HDIM + col] : 0.f;
            bv[j] = f2bf(v);
        }
        *(bf16x8*)&btab[f * 8] = bv;
    }
    // ---- bias fold: biasT[col] = b1[col] + sum_k shf[k]*W1[k][col] ----
    {
        const int col  = tid & 127;
        const int half = tid >> 7;
        float s = 0.f;
        for (int k = half * 136; k < half * 136 + 136; ++k)
            s += shf[k] * W1[k * HDIM + col];
        bias2[half][col] = s;
    }
    __syncthreads();
    if (tid < HDIM) biasT[tid] = b1[tid] + bias2[0][tid] + bias2[1][tid];
    __syncthreads();
    // ---- after this point: NO barriers; btab/biasT are read-only ----

    float biasv[8], w2v[8];
    #pragma unroll
    for (int cb = 0; cb < 8; ++cb) {
        biasv[cb] = biasT[cb * 16 + lr];
        w2v[cb]   = W2[cb * 16 + lr];
    }
    const float b2v = b2[0];
    const bool evn = !(lr & 1);

    const int gw = blockIdx.x * 4 + (tid >> 6);
    const int NW = gridDim.x * 4;

    for (int it = gw; it < nIter; it += NW) {
        const int e0 = it * 16;
        const int e  = e0 + lr;
        const int ec = (e < E) ? e : E - 1;
        const int is = index[ec];
        const int ir = index[E + ec];

        // -------- gather: 18 independent f32x4 loads, all issued up front ----
        const f32x4* ps = (const f32x4*)(x_send + (size_t)is * HDIM);
        const f32x4* pr = (const f32x4*)(x_rec  + (size_t)ir * HDIM);
        f32x4 Ls[8], Lr[8], La[2];
        #pragma unroll
        for (int kk = 0; kk < 4; ++kk) {
            Ls[kk * 2]     = ps[kk * 8 + lg * 2];
            Ls[kk * 2 + 1] = ps[kk * 8 + lg * 2 + 1];
            Lr[kk * 2]     = pr[kk * 8 + lg * 2];
            Lr[kk * 2 + 1] = pr[kk * 8 + lg * 2 + 1];
        }
        if (lg < 2) {
            const f32x4* pa = (const f32x4*)(edge_attr + (size_t)ec * INVD + lg * 8);
            La[0] = pa[0]; La[1] = pa[1];
        } else {
            La[0] = (f32x4){0.f, 0.f, 0.f, 0.f};
            La[1] = (f32x4){0.f, 0.f, 0.f, 0.f};
        }

        // -------- MFMA: 9 k-steps x 8 col-blocks --------
        f32x4 acc[8];
        #pragma unroll
        for (int cb = 0; cb < 8; ++cb) acc[cb] = (f32x4){0.f, 0.f, 0.f, 0.f};

        #pragma unroll
        for (int kk = 0; kk < NKT; ++kk) {
            f32x4 lo = (kk < 4) ? Ls[kk * 2]     : (kk < 8) ? Lr[(kk - 4) * 2]     : La[0];
            f32x4 hi = (kk < 4) ? Ls[kk * 2 + 1] : (kk < 8) ? Lr[(kk - 4) * 2 + 1] : La[1];
            bf16x8 a;
            a[0] = f2bf(lo[0]); a[1] = f2bf(lo[1]); a[2] = f2bf(lo[2]); a[3] = f2bf(lo[3]);
            a[4] = f2bf(hi[0]); a[5] = f2bf(hi[1]); a[6] = f2bf(hi[2]); a[7] = f2bf(hi[3]);
            #pragma unroll
            for (int cb = 0; cb < 8; ++cb) {
                bf16x8 b = *(const bf16x8*)&btab[((kk * 8 + cb) * 64 + l) * 8];
                acc[cb] = __builtin_amdgcn_mfma_f32_16x16x32_bf16(a, b, acc[cb], 0, 0, 0);
            }
        }

        // -------- SiLU + gate dot (16-lane reduce) --------
        float p[4] = {0.f, 0.f, 0.f, 0.f};
        #pragma unroll
        for (int cb = 0; cb < 8; ++cb) {
            #pragma unroll
            for (int q = 0; q < 4; ++q) {
                float z = acc[cb][q] + biasv[cb];
                float m = z / (1.f + __expf(-z));   // SiLU
                acc[cb][q] = m;
                p[q] += m * w2v[cb];
            }
        }
        #pragma unroll
        for (int q = 0; q < 4; ++q) {
            p[q] += __shfl_xor(p[q], 1, 64);
            p[q] += __shfl_xor(p[q], 2, 64);
            p[q] += __shfl_xor(p[q], 4, 64);
            p[q] += __shfl_xor(p[q], 8, 64);
        }

        // -------- gated scatter --------
        #pragma unroll
        for (int q = 0; q < 4; ++q) {
            const int row = lg * 4 + q;              // C row (edge) for this group
            if (e0 + row < E) {
                const int irq = __shfl(ir, row, 64); // receiver node of that edge
                const float g = 1.f / (1.f + __expf(-(p[q] + b2v)));
                if constexpr (WS) {
                    // pk-f16 atomics: per instr, 4 rows x 64 contiguous bytes
                    float m[8];
                    #pragma unroll
                    for (int cb = 0; cb < 8; ++cb) m[cb] = acc[cb][q] * g;
                    #pragma unroll
                    for (int c = 0; c < 4; ++c) {
                        float x0 = __shfl_xor(m[2 * c],     1, 64);
                        float x1 = __shfl_xor(m[2 * c + 1], 1, 64);
                        float va = evn ? m[2 * c] : x1;
                        float vb = evn ? x0       : m[2 * c + 1];
                        union { fp16x2 h; unsigned u; } pk;
                        pk.h = __builtin_amdgcn_cvt_pkrtz(va, vb);
                        const int col0 = evn ? (32 * c + lr) : (32 * c + 15 + lr);
                        unsigned long long a =
                            (unsigned long long)(ws + (size_t)irq * HDIM + col0);
                        asm volatile("global_atomic_pk_add_f16 %0, %1, off"
                                     :: "v"(a), "v"(pk.u) : "memory");
                    }
                } else {
                    float* orow = out + (size_t)irq * HDIM + lr;
                    #pragma unroll
                    for (int cb = 0; cb < 8; ++cb)
                        atomicAdd(orow + cb * 16, acc[cb][q] * g);
                }
            }
        }
    }
}

__global__ __launch_bounds__(256) void cvt_kernel(const __half* __restrict__ ws,
                                                  float* __restrict__ out, int n) {
    int i = (blockIdx.x * 256 + threadIdx.x) * 4;
    if (i < n) {
        const __half2* p = (const __half2*)(ws + i);
        float2 a = __half22float2(p[0]);
        float2 b = __half22float2(p[1]);
        f32x4 v = {a.x, a.y, b.x, b.y};
        *(f32x4*)(out + i) = v;
    }
}

extern "C" void kernel_launch(void* const* d_in, const int* in_sizes, int n_in,
                              void* d_out, int out_size, void* d_ws, size_t ws_size,
                              hipStream_t stream) {
    const float* x_send    = (const float*)d_in[0];
    const float* x_rec     = (const float*)d_in[1];
    const int*   index     = (const int*)d_in[2];
    const float* edge_attr = (const float*)d_in[3];
    const float* bn_gamma  = (const float*)d_in[4];
    const float* bn_beta   = (const float*)d_in[5];
    const float* bn_mean   = (const float*)d_in[6];
    const float* bn_var    = (const float*)d_in[7];
    const float* W1        = (const float*)d_in[8];
    const float* b1        = (const float*)d_in[9];
    const float* W2        = (const float*)d_in[10];
    const float* b2        = (const float*)d_in[11];
    float* out = (float*)d_out;

    const int E = in_sizes[3] / INVD;
    const int N = in_sizes[0] / HDIM;
    const int nIter = (E + 15) / 16;
    const int grid = 512;   // 2 blocks/CU (LDS-limited), barrier-free waves

    const size_t accBytes = (size_t)N * HDIM * sizeof(__half);
    if (ws_size >= accBytes) {
        __half* ws = (__half*)d_ws;
        hipMemsetAsync(ws, 0, accBytes, stream);
        etnn_kernel<true><<<grid, 256, 0, stream>>>(x_send, x_rec, index, edge_attr,
                                                    bn_gamma, bn_beta, bn_mean, bn_var,
                                                    W1, b1, W2, b2, out, ws, E, nIter);
        const int n = N * HDIM;
        cvt_kernel<<<(n / 4 + 255) / 256, 256, 0, stream>>>(ws, out, n);
    } else {
        hipMemsetAsync(d_out, 0, (size_t)out_size * sizeof(float), stream);
        etnn_kernel<false><<<grid, 256, 0, stream>>>(x_send, x_rec, index, edge_attr,
                                                     bn_gamma, bn_beta, bn_mean, bn_var,
                                                     W1, b1, W2, b2, out, nullptr, E, nIter);
    }
}